// Round 1
// baseline (446.441 us; speedup 1.0000x reference)
//
#include <hip/hip_runtime.h>

#define T 2048
#define SD 1024
#define ED 1024
#define HID 150
#define MAXW 10

// ---------------------------------------------------------------------------
// Kernel 1: per-token MLP score.
// 4 tokens per block, 256 threads (4 waves). Each wave owns hidden units
// j = wave, wave+4, ... and reuses the w1 row (held in 16 VGPRs) across the
// 4 tokens -> w1 L2 traffic cut 4x vs one-token-per-block.
// ---------------------------------------------------------------------------
__global__ __launch_bounds__(256) void mlp_scores_kernel(
    const float* __restrict__ states,
    const float* __restrict__ w1, const float* __restrict__ b1,
    const float* __restrict__ w2, const float* __restrict__ b2,
    const float* __restrict__ w3, const float* __restrict__ b3,
    float* __restrict__ attns)
{
    const int t0 = blockIdx.x * 4;
    __shared__ float s_state[4][1024];
    __shared__ float s_h1[4][192];   // padded to 192, zero-filled tail
    __shared__ float s_h2[4][192];
    const int tid = threadIdx.x;

    // zero-init the padded hidden buffers (tail must be 0 for guard-free dots)
    for (int i = tid; i < 4 * 192; i += 256) {
        (&s_h1[0][0])[i] = 0.f;
        (&s_h2[0][0])[i] = 0.f;
    }
    // stage 4 state rows (4096 floats = 1024 float4)
    {
        const float4* src = (const float4*)(states + (size_t)t0 * SD);
        float4* dst = (float4*)(&s_state[0][0]);
        for (int i = tid; i < 4 * SD / 4; i += 256) dst[i] = src[i];
    }
    __syncthreads();

    const int lane = tid & 63;
    const int wave = tid >> 6;

    // ---- layer 1: h1 = relu(states @ w1^T + b1) ----
    for (int j = wave; j < HID; j += 4) {
        const float* wrow = w1 + (size_t)j * SD;
        float wr[16];
#pragma unroll
        for (int m = 0; m < 16; ++m) wr[m] = wrow[lane + 64 * m];
        const float bj = b1[j];
#pragma unroll
        for (int t = 0; t < 4; ++t) {
            float acc = 0.f;
#pragma unroll
            for (int m = 0; m < 16; ++m) acc += s_state[t][lane + 64 * m] * wr[m];
#pragma unroll
            for (int off = 32; off > 0; off >>= 1) acc += __shfl_down(acc, off, 64);
            if (lane == 0) s_h1[t][j] = fmaxf(acc + bj, 0.f);
        }
    }
    __syncthreads();

    // ---- layer 2: h2 = relu(h1 @ w2^T + b2) ----
    for (int j = wave; j < HID; j += 4) {
        const float* wrow = w2 + (size_t)j * HID;
        const float wa = wrow[lane];
        const float wb = wrow[lane + 64];
        const float wc = (lane + 128 < HID) ? wrow[lane + 128] : 0.f;
        const float bj = b2[j];
#pragma unroll
        for (int t = 0; t < 4; ++t) {
            float acc = s_h1[t][lane] * wa + s_h1[t][lane + 64] * wb
                      + s_h1[t][lane + 128] * wc;
#pragma unroll
            for (int off = 32; off > 0; off >>= 1) acc += __shfl_down(acc, off, 64);
            if (lane == 0) s_h2[t][j] = fmaxf(acc + bj, 0.f);
        }
    }
    __syncthreads();

    // ---- layer 3: scalar score; wave t handles token t ----
    {
        const int t = wave;
        const float wa = w3[lane];
        const float wb = w3[lane + 64];
        const float wc = (lane + 128 < HID) ? w3[lane + 128] : 0.f;
        float acc = s_h2[t][lane] * wa + s_h2[t][lane + 64] * wb
                  + s_h2[t][lane + 128] * wc;
#pragma unroll
        for (int off = 32; off > 0; off >>= 1) acc += __shfl_down(acc, off, 64);
        if (lane == 0) attns[t0 + t] = acc + b3[0];
    }
}

// ---------------------------------------------------------------------------
// Kernel 2: one block per output row (n, s).
// Each thread owns one float4 column chunk of each 1024-wide segment:
//   [states[s] | states[s+n-1] | softmax(attns[s..s+n-1]) @ embeds[s..s+n-1]]
// ---------------------------------------------------------------------------
__global__ __launch_bounds__(256) void span_kernel(
    const float* __restrict__ embeds,
    const float* __restrict__ states,
    const float* __restrict__ attns,
    float* __restrict__ out)
{
    const int row = blockIdx.x;

    // locate (n, s): rows are grouped by span width n = 1..10
    int n = 1, base = 0;
    while (row - base >= T - n + 1) { base += T - n + 1; ++n; }
    const int s = row - base;

    // softmax over the <=10-wide window, redundantly per thread (broadcast loads)
    float a[MAXW];
    float mx = -3.4e38f;
    for (int i = 0; i < n; ++i) { a[i] = attns[s + i]; mx = fmaxf(mx, a[i]); }
    float sum = 0.f;
    for (int i = 0; i < n; ++i) { a[i] = expf(a[i] - mx); sum += a[i]; }
    const float inv = 1.f / sum;

    const int c = threadIdx.x;  // float4 index 0..255 within a 1024-float segment
    float4* orow = (float4*)(out + (size_t)row * 3072);
    const float4* st0 = (const float4*)(states + (size_t)s * SD);
    const float4* st1 = (const float4*)(states + (size_t)(s + n - 1) * SD);

    orow[c]       = st0[c];
    orow[256 + c] = st1[c];

    float4 p = make_float4(0.f, 0.f, 0.f, 0.f);
    for (int i = 0; i < n; ++i) {
        const float w = a[i] * inv;
        const float4 e = ((const float4*)(embeds + (size_t)(s + i) * ED))[c];
        p.x += w * e.x; p.y += w * e.y; p.z += w * e.z; p.w += w * e.w;
    }
    orow[512 + c] = p;
}

extern "C" void kernel_launch(void* const* d_in, const int* in_sizes, int n_in,
                              void* d_out, int out_size, void* d_ws, size_t ws_size,
                              hipStream_t stream) {
    const float* embeds = (const float*)d_in[0];
    const float* states = (const float*)d_in[1];
    const float* w1 = (const float*)d_in[2];
    const float* b1 = (const float*)d_in[3];
    const float* w2 = (const float*)d_in[4];
    const float* b2 = (const float*)d_in[5];
    const float* w3 = (const float*)d_in[6];
    const float* b3 = (const float*)d_in[7];
    float* out = (float*)d_out;
    float* attns = (float*)d_ws;  // T floats of scratch

    mlp_scores_kernel<<<T / 4, 256, 0, stream>>>(states, w1, b1, w2, b2, w3, b3, attns);

    int nrows = 0;
    for (int n = 1; n <= MAXW; ++n) nrows += T - n + 1;  // 20435
    span_kernel<<<nrows, 256, 0, stream>>>(embeds, states, attns, out);
}

// Round 3
// 425.306 us; speedup vs baseline: 1.0497x; 1.0497x over previous
//
#include <hip/hip_runtime.h>

#define T 2048
#define SD 1024
#define ED 1024
#define HID 150
#define MAXW 10

typedef float f32x4 __attribute__((ext_vector_type(4)));  // native vec type:
// __builtin_nontemporal_store accepts this, unlike HIP's float4 class.

// ---------------------------------------------------------------------------
// Kernel 1: per-token MLP score.
// 4 tokens per block, 256 threads (4 waves). Each wave owns hidden-unit PAIRS
// (j, j+1) stepping by 8; the two w1 rows are held in 8 float4 registers and
// reused across the 4 tokens. States are read from LDS as contiguous
// ds_read_b128 (lane partition idx = m*64 + lane — conflict-free), and
// each LDS read feeds TWO hidden units (j-unroll 2 halves LDS traffic).
// ---------------------------------------------------------------------------
__global__ __launch_bounds__(256) void mlp_scores_kernel(
    const float* __restrict__ states,
    const float* __restrict__ w1, const float* __restrict__ b1,
    const float* __restrict__ w2, const float* __restrict__ b2,
    const float* __restrict__ w3, const float* __restrict__ b3,
    float* __restrict__ attns)
{
    const int t0 = blockIdx.x * 4;
    __shared__ float4 s_state[4][256];
    __shared__ float s_h1[4][192];   // padded to 192, zero-filled tail
    __shared__ float s_h2[4][192];
    const int tid = threadIdx.x;

    for (int i = tid; i < 4 * 192; i += 256) {
        (&s_h1[0][0])[i] = 0.f;
        (&s_h2[0][0])[i] = 0.f;
    }
    {
        const float4* src = (const float4*)(states + (size_t)t0 * SD);
        float4* dst = &s_state[0][0];
        for (int i = tid; i < 4 * SD / 4; i += 256) dst[i] = src[i];
    }
    __syncthreads();

    const int lane = tid & 63;
    const int wave = tid >> 6;

    // ---- layer 1: h1 = relu(states @ w1^T + b1), two j per iteration ----
    for (int j = wave * 2; j < HID; j += 8) {
        const float4* w4a = (const float4*)(w1 + (size_t)j * SD);
        const float4* w4b = (const float4*)(w1 + (size_t)(j + 1) * SD);
        float4 wra[4], wrb[4];
#pragma unroll
        for (int m = 0; m < 4; ++m) {
            wra[m] = w4a[m * 64 + lane];   // lanes cover contiguous 1 KB
            wrb[m] = w4b[m * 64 + lane];
        }
        const float bja = b1[j];
        const float bjb = b1[j + 1];
#pragma unroll
        for (int t = 0; t < 4; ++t) {
            float acc0 = 0.f, acc1 = 0.f;
#pragma unroll
            for (int m = 0; m < 4; ++m) {
                const float4 sv = s_state[t][m * 64 + lane];  // ds_read_b128
                acc0 += sv.x * wra[m].x + sv.y * wra[m].y
                      + sv.z * wra[m].z + sv.w * wra[m].w;
                acc1 += sv.x * wrb[m].x + sv.y * wrb[m].y
                      + sv.z * wrb[m].z + sv.w * wrb[m].w;
            }
#pragma unroll
            for (int off = 32; off > 0; off >>= 1) {
                acc0 += __shfl_down(acc0, off, 64);
                acc1 += __shfl_down(acc1, off, 64);
            }
            if (lane == 0) {
                s_h1[t][j]     = fmaxf(acc0 + bja, 0.f);
                s_h1[t][j + 1] = fmaxf(acc1 + bjb, 0.f);
            }
        }
    }
    __syncthreads();

    // ---- layer 2: h2 = relu(h1 @ w2^T + b2) ----
    for (int j = wave; j < HID; j += 4) {
        const float* wrow = w2 + (size_t)j * HID;
        const float wa = wrow[lane];
        const float wb = wrow[lane + 64];
        const float wc = (lane + 128 < HID) ? wrow[lane + 128] : 0.f;
        const float bj = b2[j];
#pragma unroll
        for (int t = 0; t < 4; ++t) {
            float acc = s_h1[t][lane] * wa + s_h1[t][lane + 64] * wb
                      + s_h1[t][lane + 128] * wc;
#pragma unroll
            for (int off = 32; off > 0; off >>= 1) acc += __shfl_down(acc, off, 64);
            if (lane == 0) s_h2[t][j] = fmaxf(acc + bj, 0.f);
        }
    }
    __syncthreads();

    // ---- layer 3: scalar score; wave t handles token t ----
    {
        const int t = wave;
        const float wa = w3[lane];
        const float wb = w3[lane + 64];
        const float wc = (lane + 128 < HID) ? w3[lane + 128] : 0.f;
        float acc = s_h2[t][lane] * wa + s_h2[t][lane + 64] * wb
                  + s_h2[t][lane + 128] * wc;
#pragma unroll
        for (int off = 32; off > 0; off >>= 1) acc += __shfl_down(acc, off, 64);
        if (lane == 0) attns[t0 + t] = acc + b3[0];
    }
}

// ---------------------------------------------------------------------------
// Kernel 2: one block per output row (n, s). NO private arrays (a runtime-
// bound loop over a local array forces scratch) — softmax is recomputed in
// three broadcast-load passes over attns instead. Output stores are
// non-temporal (write-once, 251 MB — keep L2 for embeds/states).
// ---------------------------------------------------------------------------
__global__ __launch_bounds__(256) void span_kernel(
    const float* __restrict__ embeds,
    const float* __restrict__ states,
    const float* __restrict__ attns,
    float* __restrict__ out)
{
    const int row = blockIdx.x;

    int n = 1, base = 0;
    while (row - base >= T - n + 1) { base += T - n + 1; ++n; }
    const int s = row - base;

    // pass 1: max; pass 2: sum of exp  (all loads broadcast / L1-resident)
    float mx = -3.4e38f;
    for (int i = 0; i < n; ++i) mx = fmaxf(mx, attns[s + i]);
    float sum = 0.f;
    for (int i = 0; i < n; ++i) sum += expf(attns[s + i] - mx);
    const float inv = 1.f / sum;

    const int c = threadIdx.x;  // float4 index within a 1024-float segment
    f32x4* orow = (f32x4*)(out + (size_t)row * 3072);
    const f32x4* st0 = (const f32x4*)(states + (size_t)s * SD);
    const f32x4* st1 = (const f32x4*)(states + (size_t)(s + n - 1) * SD);

    __builtin_nontemporal_store(st0[c], &orow[c]);
    __builtin_nontemporal_store(st1[c], &orow[256 + c]);

    f32x4 p = (f32x4)(0.f);
    for (int i = 0; i < n; ++i) {
        const float w = expf(attns[s + i] - mx) * inv;  // pass 3, fused
        const f32x4 e = ((const f32x4*)(embeds + (size_t)(s + i) * ED))[c];
        p += w * e;
    }
    __builtin_nontemporal_store(p, &orow[512 + c]);
}

extern "C" void kernel_launch(void* const* d_in, const int* in_sizes, int n_in,
                              void* d_out, int out_size, void* d_ws, size_t ws_size,
                              hipStream_t stream) {
    const float* embeds = (const float*)d_in[0];
    const float* states = (const float*)d_in[1];
    const float* w1 = (const float*)d_in[2];
    const float* b1 = (const float*)d_in[3];
    const float* w2 = (const float*)d_in[4];
    const float* b2 = (const float*)d_in[5];
    const float* w3 = (const float*)d_in[6];
    const float* b3 = (const float*)d_in[7];
    float* out = (float*)d_out;
    float* attns = (float*)d_ws;  // T floats of scratch

    mlp_scores_kernel<<<T / 4, 256, 0, stream>>>(states, w1, b1, w2, b2, w3, b3, attns);

    int nrows = 0;
    for (int n = 1; n <= MAXW; ++n) nrows += T - n + 1;  // 20435
    span_kernel<<<nrows, 256, 0, stream>>>(embeds, states, attns, out);
}

// Round 4
// 369.153 us; speedup vs baseline: 1.2094x; 1.1521x over previous
//
#include <hip/hip_runtime.h>

#define T 2048
#define SD 1024
#define ED 1024
#define HID 150
#define MAXW 10

typedef float f32x4 __attribute__((ext_vector_type(4)));

// ---------------------------------------------------------------------------
// Kernel 1: per-token MLP score -> stores exp(score) (softmax numerator).
// Max-subtraction cancels exactly in softmax ratios; scores are O(0.1) so
// exp cannot overflow. 4 tokens/block, 256 threads.
// ---------------------------------------------------------------------------
__global__ __launch_bounds__(256) void mlp_scores_kernel(
    const float* __restrict__ states,
    const float* __restrict__ w1, const float* __restrict__ b1,
    const float* __restrict__ w2, const float* __restrict__ b2,
    const float* __restrict__ w3, const float* __restrict__ b3,
    float* __restrict__ expA)
{
    const int t0 = blockIdx.x * 4;
    __shared__ float4 s_state[4][256];
    __shared__ float s_h1[4][192];   // padded to 192, zero-filled tail
    __shared__ float s_h2[4][192];
    const int tid = threadIdx.x;

    for (int i = tid; i < 4 * 192; i += 256) {
        (&s_h1[0][0])[i] = 0.f;
        (&s_h2[0][0])[i] = 0.f;
    }
    {
        const float4* src = (const float4*)(states + (size_t)t0 * SD);
        float4* dst = &s_state[0][0];
        for (int i = tid; i < 4 * SD / 4; i += 256) dst[i] = src[i];
    }
    __syncthreads();

    const int lane = tid & 63;
    const int wave = tid >> 6;

    // ---- layer 1: h1 = relu(states @ w1^T + b1), two j per iteration ----
    for (int j = wave * 2; j < HID; j += 8) {
        const float4* w4a = (const float4*)(w1 + (size_t)j * SD);
        const float4* w4b = (const float4*)(w1 + (size_t)(j + 1) * SD);
        float4 wra[4], wrb[4];
#pragma unroll
        for (int m = 0; m < 4; ++m) {
            wra[m] = w4a[m * 64 + lane];
            wrb[m] = w4b[m * 64 + lane];
        }
        const float bja = b1[j];
        const float bjb = b1[j + 1];
#pragma unroll
        for (int t = 0; t < 4; ++t) {
            float acc0 = 0.f, acc1 = 0.f;
#pragma unroll
            for (int m = 0; m < 4; ++m) {
                const float4 sv = s_state[t][m * 64 + lane];  // ds_read_b128
                acc0 += sv.x * wra[m].x + sv.y * wra[m].y
                      + sv.z * wra[m].z + sv.w * wra[m].w;
                acc1 += sv.x * wrb[m].x + sv.y * wrb[m].y
                      + sv.z * wrb[m].z + sv.w * wrb[m].w;
            }
#pragma unroll
            for (int off = 32; off > 0; off >>= 1) {
                acc0 += __shfl_down(acc0, off, 64);
                acc1 += __shfl_down(acc1, off, 64);
            }
            if (lane == 0) {
                s_h1[t][j]     = fmaxf(acc0 + bja, 0.f);
                s_h1[t][j + 1] = fmaxf(acc1 + bjb, 0.f);
            }
        }
    }
    __syncthreads();

    // ---- layer 2: h2 = relu(h1 @ w2^T + b2) ----
    for (int j = wave; j < HID; j += 4) {
        const float* wrow = w2 + (size_t)j * HID;
        const float wa = wrow[lane];
        const float wb = wrow[lane + 64];
        const float wc = (lane + 128 < HID) ? wrow[lane + 128] : 0.f;
        const float bj = b2[j];
#pragma unroll
        for (int t = 0; t < 4; ++t) {
            float acc = s_h1[t][lane] * wa + s_h1[t][lane + 64] * wb
                      + s_h1[t][lane + 128] * wc;
#pragma unroll
            for (int off = 32; off > 0; off >>= 1) acc += __shfl_down(acc, off, 64);
            if (lane == 0) s_h2[t][j] = fmaxf(acc + bj, 0.f);
        }
    }
    __syncthreads();

    // ---- layer 3: scalar score; wave t handles token t ----
    {
        const int t = wave;
        const float wa = w3[lane];
        const float wb = w3[lane + 64];
        const float wc = (lane + 128 < HID) ? w3[lane + 128] : 0.f;
        float acc = s_h2[t][lane] * wa + s_h2[t][lane + 64] * wb
                  + s_h2[t][lane + 128] * wc;
#pragma unroll
        for (int off = 32; off > 0; off >>= 1) acc += __shfl_down(acc, off, 64);
        if (lane == 0) expA[t0 + t] = expf(acc + b3[0]);
    }
}

// ---------------------------------------------------------------------------
// Kernel 2: one block per START POSITION s (2048 blocks). All span widths
// n=1..10 for this s are produced incrementally via prefix sums:
//   P_n = sum_{i<n} expA[s+i] * embeds[s+i],  S_n = sum_{i<n} expA[s+i]
//   pooled_n = P_n / S_n   (softmax max-shift cancels exactly)
// Each embeds/states row is read ONCE per block (~170 MB logical reads vs
// 617 MB in the width-grouped layout); states[s] is register-reused across
// all 10 output rows; zero expf in this kernel. Output rows for width n
// live at (base_n + s) — base_n tracked by a running sum.
// ---------------------------------------------------------------------------
__global__ __launch_bounds__(256) void span_kernel(
    const float* __restrict__ embeds,
    const float* __restrict__ states,
    const float* __restrict__ expA,
    float* __restrict__ out)
{
    const int s = blockIdx.x;
    const int c = threadIdx.x;  // float4 index within a 1024-float segment

    const f32x4 st_s = ((const f32x4*)(states + (size_t)s * SD))[c];

    f32x4 P = (f32x4)(0.f);
    float S = 0.f;
    int base = 0;

    for (int i = 0; i < MAXW; ++i) {
        if (s + i < T) {
            const float E = expA[s + i];                      // broadcast load
            const f32x4 e  = ((const f32x4*)(embeds + (size_t)(s + i) * ED))[c];
            const f32x4 se = ((const f32x4*)(states + (size_t)(s + i) * SD))[c];
            P += E * e;
            S += E;
            const float inv = 1.f / S;
            f32x4* orow = (f32x4*)(out + (size_t)(base + s) * 3072);
            __builtin_nontemporal_store(st_s,    &orow[c]);
            __builtin_nontemporal_store(se,      &orow[256 + c]);
            __builtin_nontemporal_store(P * inv, &orow[512 + c]);
        }
        base += T - i;  // advance by rows of width n=i+1: (T - n + 1)
    }
}

extern "C" void kernel_launch(void* const* d_in, const int* in_sizes, int n_in,
                              void* d_out, int out_size, void* d_ws, size_t ws_size,
                              hipStream_t stream) {
    const float* embeds = (const float*)d_in[0];
    const float* states = (const float*)d_in[1];
    const float* w1 = (const float*)d_in[2];
    const float* b1 = (const float*)d_in[3];
    const float* w2 = (const float*)d_in[4];
    const float* b2 = (const float*)d_in[5];
    const float* w3 = (const float*)d_in[6];
    const float* b3 = (const float*)d_in[7];
    float* out = (float*)d_out;
    float* expA = (float*)d_ws;  // T floats of scratch

    mlp_scores_kernel<<<T / 4, 256, 0, stream>>>(states, w1, b1, w2, b2, w3, b3, expA);
    span_kernel<<<T, 256, 0, stream>>>(embeds, states, expA, out);
}

// Round 5
// 354.229 us; speedup vs baseline: 1.2603x; 1.0421x over previous
//
#include <hip/hip_runtime.h>

#define T 2048
#define SD 1024
#define ED 1024
#define HID 150
#define MAXW 10

typedef float f32x4 __attribute__((ext_vector_type(4)));

// ---------------------------------------------------------------------------
// Kernel 1: per-token MLP score -> stores exp(score) (softmax numerator).
// 4 tokens/block, 256 threads. Layer-1 w1 row-pairs are DOUBLE-BUFFERED in
// registers: next pair's 8 float4 loads issue before the current pair's
// compute, hiding L2/L3 latency at 2 waves/SIMD occupancy.
// ---------------------------------------------------------------------------
__global__ __launch_bounds__(256) void mlp_scores_kernel(
    const float* __restrict__ states,
    const float* __restrict__ w1, const float* __restrict__ b1,
    const float* __restrict__ w2, const float* __restrict__ b2,
    const float* __restrict__ w3, const float* __restrict__ b3,
    float* __restrict__ expA)
{
    const int t0 = blockIdx.x * 4;
    __shared__ float4 s_state[4][256];
    __shared__ float s_h1[4][192];   // padded to 192, zero-filled tail
    __shared__ float s_h2[4][192];
    const int tid = threadIdx.x;

    for (int i = tid; i < 4 * 192; i += 256) {
        (&s_h1[0][0])[i] = 0.f;
        (&s_h2[0][0])[i] = 0.f;
    }
    {
        const float4* src = (const float4*)(states + (size_t)t0 * SD);
        float4* dst = &s_state[0][0];
        for (int i = tid; i < 4 * SD / 4; i += 256) dst[i] = src[i];
    }
    __syncthreads();

    const int lane = tid & 63;
    const int wave = tid >> 6;

    // ---- layer 1: h1 = relu(states @ w1^T + b1), j-pairs, double-buffered ----
    {
        int j = wave * 2;
        float4 wra[4], wrb[4];
        {
            const float4* w4a = (const float4*)(w1 + (size_t)j * SD);
#pragma unroll
            for (int m = 0; m < 4; ++m) {
                wra[m] = w4a[m * 64 + lane];
                wrb[m] = w4a[256 + m * 64 + lane];
            }
        }
        while (j < HID) {
            const int jn = j + 8;
            const int jp = (jn < HID) ? jn : j;   // clamp: last iter reloads self
            float4 nra[4], nrb[4];
            {
                const float4* n4a = (const float4*)(w1 + (size_t)jp * SD);
#pragma unroll
                for (int m = 0; m < 4; ++m) {      // prefetch BEFORE compute
                    nra[m] = n4a[m * 64 + lane];
                    nrb[m] = n4a[256 + m * 64 + lane];
                }
            }
            const float bja = b1[j];
            const float bjb = b1[j + 1];
#pragma unroll
            for (int t = 0; t < 4; ++t) {
                float acc0 = 0.f, acc1 = 0.f;
#pragma unroll
                for (int m = 0; m < 4; ++m) {
                    const float4 sv = s_state[t][m * 64 + lane];  // ds_read_b128
                    acc0 += sv.x * wra[m].x + sv.y * wra[m].y
                          + sv.z * wra[m].z + sv.w * wra[m].w;
                    acc1 += sv.x * wrb[m].x + sv.y * wrb[m].y
                          + sv.z * wrb[m].z + sv.w * wrb[m].w;
                }
#pragma unroll
                for (int off = 32; off > 0; off >>= 1) {
                    acc0 += __shfl_down(acc0, off, 64);
                    acc1 += __shfl_down(acc1, off, 64);
                }
                if (lane == 0) {
                    s_h1[t][j]     = fmaxf(acc0 + bja, 0.f);
                    s_h1[t][j + 1] = fmaxf(acc1 + bjb, 0.f);
                }
            }
#pragma unroll
            for (int m = 0; m < 4; ++m) { wra[m] = nra[m]; wrb[m] = nrb[m]; }
            j = jn;
        }
    }
    __syncthreads();

    // ---- layer 2: h2 = relu(h1 @ w2^T + b2) ----
    for (int j = wave; j < HID; j += 4) {
        const float* wrow = w2 + (size_t)j * HID;
        const float wa = wrow[lane];
        const float wb = wrow[lane + 64];
        const float wc = (lane + 128 < HID) ? wrow[lane + 128] : 0.f;
        const float bj = b2[j];
#pragma unroll
        for (int t = 0; t < 4; ++t) {
            float acc = s_h1[t][lane] * wa + s_h1[t][lane + 64] * wb
                      + s_h1[t][lane + 128] * wc;
#pragma unroll
            for (int off = 32; off > 0; off >>= 1) acc += __shfl_down(acc, off, 64);
            if (lane == 0) s_h2[t][j] = fmaxf(acc + bj, 0.f);
        }
    }
    __syncthreads();

    // ---- layer 3: scalar score; wave t handles token t ----
    {
        const int t = wave;
        const float wa = w3[lane];
        const float wb = w3[lane + 64];
        const float wc = (lane + 128 < HID) ? w3[lane + 128] : 0.f;
        float acc = s_h2[t][lane] * wa + s_h2[t][lane + 64] * wb
                  + s_h2[t][lane + 128] * wc;
#pragma unroll
        for (int off = 32; off > 0; off >>= 1) acc += __shfl_down(acc, off, 64);
        if (lane == 0) expA[t0 + t] = expf(acc + b3[0]);
    }
}

// ---------------------------------------------------------------------------
// Kernel 2: one block per start position s; widths 1..10 via prefix sums
// (softmax max-shift cancels exactly; scores are O(0.1)).
// NORMAL stores this round (the only 6.4 TB/s write evidence on this box —
// harness fills, m13 copy — uses normal stores; NT is unproven on gfx950).
// Main path (s <= T-MAXW) is guard-free and fully unrolled so all 21 loads
// can issue ahead of the serial P/S chain.
// ---------------------------------------------------------------------------
__global__ __launch_bounds__(256) void span_kernel(
    const float* __restrict__ embeds,
    const float* __restrict__ states,
    const float* __restrict__ expA,
    float* __restrict__ out)
{
    const int s = blockIdx.x;
    const int c = threadIdx.x;  // float4 index within a 1024-float segment

    const f32x4 st_s = ((const f32x4*)(states + (size_t)s * SD))[c];

    f32x4 P = (f32x4)(0.f);
    float S = 0.f;

    if (s <= T - MAXW) {
        int base = 0;
#pragma unroll
        for (int i = 0; i < MAXW; ++i) {
            const float E = expA[s + i];
            const f32x4 e  = ((const f32x4*)(embeds + (size_t)(s + i) * ED))[c];
            const f32x4 se = ((const f32x4*)(states + (size_t)(s + i) * SD))[c];
            P += E * e;
            S += E;
            const float inv = 1.f / S;
            f32x4* orow = (f32x4*)(out + (size_t)(base + s) * 3072);
            orow[c]       = st_s;
            orow[256 + c] = se;
            orow[512 + c] = P * inv;
            base += T - i;
        }
    } else {
        int base = 0;
        for (int i = 0; i < MAXW; ++i) {
            if (s + i < T) {
                const float E = expA[s + i];
                const f32x4 e  = ((const f32x4*)(embeds + (size_t)(s + i) * ED))[c];
                const f32x4 se = ((const f32x4*)(states + (size_t)(s + i) * SD))[c];
                P += E * e;
                S += E;
                const float inv = 1.f / S;
                f32x4* orow = (f32x4*)(out + (size_t)(base + s) * 3072);
                orow[c]       = st_s;
                orow[256 + c] = se;
                orow[512 + c] = P * inv;
            }
            base += T - i;
        }
    }
}

extern "C" void kernel_launch(void* const* d_in, const int* in_sizes, int n_in,
                              void* d_out, int out_size, void* d_ws, size_t ws_size,
                              hipStream_t stream) {
    const float* embeds = (const float*)d_in[0];
    const float* states = (const float*)d_in[1];
    const float* w1 = (const float*)d_in[2];
    const float* b1 = (const float*)d_in[3];
    const float* w2 = (const float*)d_in[4];
    const float* b2 = (const float*)d_in[5];
    const float* w3 = (const float*)d_in[6];
    const float* b3 = (const float*)d_in[7];
    float* out = (float*)d_out;
    float* expA = (float*)d_ws;  // T floats of scratch

    mlp_scores_kernel<<<T / 4, 256, 0, stream>>>(states, w1, b1, w2, b2, w3, b3, expA);
    span_kernel<<<T, 256, 0, stream>>>(embeds, states, expA, out);
}